// Round 11
// baseline (313.919 us; speedup 1.0000x reference)
//
#include <hip/hip_runtime.h>
#include <hip/hip_bf16.h>

// GCNLayer: CSR build + 2 XCD-affine feature-sliced SpMM hops (fp32) +
// 3 fused GEMMs via bf16 hi/lo split MFMA (3x v_mfma_f32_16x16x32_bf16
// per fp32 product), double-buffered LDS 2-phase pipeline.
// out[r*1536 + hop*512 + c] = relu(h_hop @ W[hop] + b[hop])

#define IN_DIM 512
#define OUT_DIM 512

typedef float f32x4 __attribute__((ext_vector_type(4)));
typedef unsigned short u16x8 __attribute__((ext_vector_type(8)));

__device__ inline unsigned short f2bf(float x) {
    union { float f; unsigned u; } v; v.f = x;
    unsigned r = v.u + 0x7fff + ((v.u >> 16) & 1);   // round-to-nearest-even
    return (unsigned short)(r >> 16);
}
__device__ inline float bf2f(unsigned short h) {
    union { float f; unsigned u; } v; v.u = ((unsigned)h) << 16;
    return v.f;
}

__device__ inline void gld_lds16(const void* g, void* l) {
    __builtin_amdgcn_global_load_lds(
        (const __attribute__((address_space(1))) unsigned*)g,
        (__attribute__((address_space(3))) unsigned*)l, 16, 0, 0);
}

__device__ inline void mfma16(f32x4& d, u16x8 a, u16x8 b) {
    asm("v_mfma_f32_16x16x32_bf16 %0, %1, %2, %0" : "+v"(d) : "v"(a), "v"(b));
}

// ---------------- CSR build ----------------

__global__ __launch_bounds__(256) void hist_kernel(const int* __restrict__ dst,
                                                   int* __restrict__ counts, int E) {
    int e = blockIdx.x * blockDim.x + threadIdx.x;
    if (e < E) atomicAdd(&counts[dst[e]], 1);
}

__global__ __launch_bounds__(1024) void scan_kernel(const int* __restrict__ counts,
                                                    int* __restrict__ offs,
                                                    int* __restrict__ cursor, int n) {
    __shared__ int partials[16];
    const int tid = threadIdx.x;
    const int chunk = (n + 1023) / 1024;
    const int start = tid * chunk;
    const int end = min(start + chunk, n);

    int sum = 0;
    for (int i = start; i < end; ++i) sum += counts[i];

    const int lane = tid & 63;
    const int wave = tid >> 6;
    int v = sum;
    #pragma unroll
    for (int d = 1; d < 64; d <<= 1) {
        int up = __shfl_up(v, d, 64);
        if (lane >= d) v += up;
    }
    if (lane == 63) partials[wave] = v;
    __syncthreads();
    if (tid == 0) {
        int acc = 0;
        #pragma unroll
        for (int w = 0; w < 16; ++w) { int t = partials[w]; partials[w] = acc; acc += t; }
    }
    __syncthreads();

    int run = partials[wave] + (v - sum);
    for (int i = start; i < end; ++i) {
        offs[i] = run;
        cursor[i] = run;
        run += counts[i];
    }
    if (end == n) offs[n] = run;
}

__global__ __launch_bounds__(256) void scatter_kernel(const int* __restrict__ src,
                                                      const int* __restrict__ dst,
                                                      const float* __restrict__ edge_w,
                                                      int* __restrict__ cursor,
                                                      int* __restrict__ esrc,
                                                      float* __restrict__ eww, int E) {
    int e = blockIdx.x * blockDim.x + threadIdx.x;
    if (e < E) {
        int d = dst[e];
        int pos = atomicAdd(&cursor[d], 1);
        esrc[pos] = src[e];
        eww[pos] = edge_w[e];
    }
}

// ---------------- XCD-affine sliced SpMM hop (unchanged, under test) -------
// hout[v, f] = D[v] * sum_{e: dst=v} w_e * hin[src_e, f]
// slice = bid & 7: with round-robin block->XCD dispatch each XCD touches one
// 10000 x 64 column slice (2.56 MB) -> gather L2-resident.

__global__ __launch_bounds__(256) void hop_slice_kernel(const float* __restrict__ hin,
                                                        const float* __restrict__ Dn,
                                                        const int* __restrict__ offs,
                                                        const int* __restrict__ esrc,
                                                        const float* __restrict__ eww,
                                                        float* __restrict__ hout, int N) {
    const int bid = blockIdx.x;
    const int slice = bid & 7;
    const int wv = threadIdx.x >> 6;
    const int v = (bid >> 3) * 4 + wv;
    if (v >= N) return;
    const int f = slice * 64 + (threadIdx.x & 63);

    const int beg = offs[v];
    const int end = offs[v + 1];
    float acc = 0.f;
    int sN = 0; float wN = 0.f;
    if (beg < end) { sN = esrc[beg]; wN = eww[beg]; }
    for (int i = beg; i < end; ++i) {
        const int s = sN;
        const float w = wN;
        if (i + 1 < end) { sN = esrc[i + 1]; wN = eww[i + 1]; }  // uniform prefetch
        acc = fmaf(hin[(size_t)s * IN_DIM + f], w, acc);
    }
    hout[(size_t)v * IN_DIM + f] = acc * Dn[v];
}

// ---------------- W transpose + bf16 hi/lo split (once per launch) ----------
// W[hop][k][n] fp32 -> WtHi/WtLo[hop][n][k] bf16

__global__ __launch_bounds__(256) void wsplit_kernel(const float* __restrict__ W,
                                                     unsigned short* __restrict__ WtHi,
                                                     unsigned short* __restrict__ WtLo) {
    const int t = blockIdx.x * 256 + threadIdx.x;   // 3*512*128 total
    const int kq = t & 127;
    const int n = (t >> 7) & 511;
    const int h = t >> 16;
    const float* w = W + (size_t)h * IN_DIM * OUT_DIM;
    unsigned short hi[4], lo[4];
    #pragma unroll
    for (int j = 0; j < 4; ++j) {
        const float x = w[(size_t)(kq * 4 + j) * OUT_DIM + n];
        hi[j] = f2bf(x);
        lo[j] = f2bf(x - bf2f(hi[j]));
    }
    const size_t o = (size_t)h * IN_DIM * OUT_DIM + (size_t)n * IN_DIM + kq * 4;
    *(ushort4*)&WtHi[o] = *(const ushort4*)hi;
    *(ushort4*)&WtLo[o] = *(const ushort4*)lo;
}

// ---------------- split-bf16 MFMA GEMM + bias + relu ----------------
// BM=BN=128, BK=32, 256 thr (4 waves, 2x2 of 64x64).
// Double-buffered LDS, 2-phase: issue stage(t+1) -> compute(t) -> write A(t+1)
// -> one barrier. Stage latency hides under the 48-MFMA cluster.

#define BM 128
#define BN 128
#define BK 32
#define NT (IN_DIM / BK)

__global__ __launch_bounds__(256) void gemm_split_mfma(
        const float* __restrict__ A0, const float* __restrict__ A1,
        const float* __restrict__ A2,
        const unsigned short* __restrict__ WtHi, const unsigned short* __restrict__ WtLo,
        const float* __restrict__ bias, float* __restrict__ out, int M) {

    // [buf][0=Ahi,1=Alo,2=Bhi,3=Blo][BM*BK] ushort: 2*4*8KB = 64 KB
    __shared__ unsigned short lds[2][4][BM * BK];

    const int tid = threadIdx.x;
    const int ln = tid & 63;
    const int wv = tid >> 6;
    const int hop = blockIdx.z;
    const float* __restrict__ A = hop == 0 ? A0 : hop == 1 ? A1 : A2;
    const unsigned short* __restrict__ BH = WtHi + (size_t)hop * IN_DIM * OUT_DIM;
    const unsigned short* __restrict__ BL = WtLo + (size_t)hop * IN_DIM * OUT_DIM;

    const int row0 = blockIdx.x * BM;
    const int col0 = blockIdx.y * BN;

    // A reg-stage mapping: thread -> (row=tid>>3 (+32p), 4-float k-chunk kq=tid&7)
    const int ar = tid >> 3;
    const int akq = tid & 7;
    // B DMA mapping: wave wv stages chunks {2wv, 2wv+1}; lane -> (row, 16B slot)
    const int bi = ln >> 2;
    const int bsl = ln & 3;

    const int wm = wv >> 1, wn = wv & 1;   // wave's 64x64 sub-tile
    const int fr = ln & 15, kg = ln >> 4;  // fragment row/col + k-group

    // B stage: global_load_lds, source pre-swizzled (linear LDS dest)
    auto stageB = [&](int b, int k0) {
        #pragma unroll
        for (int q = 0; q < 2; ++q) {
            const int nrow = (wv * 2 + q) * 16 + bi;          // 0..127
            const int kp = bsl ^ ((nrow >> 1) & 3);           // swizzled 16B slot
            const size_t go = (size_t)(col0 + nrow) * IN_DIM + k0 + kp * 8;
            gld_lds16(BH + go, (char*)lds[b][2] + (wv * 2 + q) * 1024);
            gld_lds16(BL + go, (char*)lds[b][3] + (wv * 2 + q) * 1024);
        }
    };
    // A: global float4 load (issue-early) ...
    auto loadA = [&](float4* apf, int k0) {
        #pragma unroll
        for (int p = 0; p < 4; ++p) {
            int gr = row0 + ar + p * 32;
            gr = gr < M ? gr : M - 1;                         // clamp; never stored
            apf[p] = *(const float4*)&A[(size_t)gr * IN_DIM + k0 + akq * 4];
        }
    };
    // ... hi/lo split + swizzled ds_write (write-late)
    auto writeA = [&](int b, const float4* apf) {
        #pragma unroll
        for (int p = 0; p < 4; ++p) {
            const int r = ar + p * 32;                        // 0..127
            const float4 av = apf[p];
            unsigned short h[4], l[4];
            h[0] = f2bf(av.x); l[0] = f2bf(av.x - bf2f(h[0]));
            h[1] = f2bf(av.y); l[1] = f2bf(av.y - bf2f(h[1]));
            h[2] = f2bf(av.z); l[2] = f2bf(av.z - bf2f(h[2]));
            h[3] = f2bf(av.w); l[3] = f2bf(av.w - bf2f(h[3]));
            const int boff = r * 64 + ((akq * 8) ^ ((((r >> 1) & 3)) << 4));
            *(ushort4*)((char*)lds[b][0] + boff) = *(const ushort4*)h;
            *(ushort4*)((char*)lds[b][1] + boff) = *(const ushort4*)l;
        }
    };

    f32x4 acc[4][4] = {};

    // prologue: stage tile 0 into buf 0
    {
        stageB(0, 0);
        float4 apf[4];
        loadA(apf, 0);
        writeA(0, apf);
    }
    __syncthreads();

    #pragma unroll 1
    for (int t = 0; t < NT; ++t) {
        const int cur = t & 1;

        // phase 1: issue next-tile staging (latency hides under MFMAs)
        float4 apf[4];
        if (t + 1 < NT) {
            stageB(cur ^ 1, (t + 1) * BK);
            loadA(apf, (t + 1) * BK);
        }

        // phase 2: compute current tile from lds[cur]
        u16x8 ah[4], al[4], bh[4], bl[4];
        #pragma unroll
        for (int mf = 0; mf < 4; ++mf) {
            const int r = wm * 64 + mf * 16 + fr;
            const int off = r * 64 + ((kg * 16) ^ ((((r >> 1) & 3)) << 4));
            ah[mf] = *(const u16x8*)((const char*)lds[cur][0] + off);
            al[mf] = *(const u16x8*)((const char*)lds[cur][1] + off);
        }
        #pragma unroll
        for (int nf = 0; nf < 4; ++nf) {
            const int n = wn * 64 + nf * 16 + fr;
            const int off = n * 64 + ((kg * 16) ^ ((((n >> 1) & 3)) << 4));
            bh[nf] = *(const u16x8*)((const char*)lds[cur][2] + off);
            bl[nf] = *(const u16x8*)((const char*)lds[cur][3] + off);
        }

        // 3 passes of 16 MFMAs: dep distance 16 on each acc register set
        #pragma unroll
        for (int mf = 0; mf < 4; ++mf)
            #pragma unroll
            for (int nf = 0; nf < 4; ++nf)
                mfma16(acc[mf][nf], al[mf], bh[nf]);
        #pragma unroll
        for (int mf = 0; mf < 4; ++mf)
            #pragma unroll
            for (int nf = 0; nf < 4; ++nf)
                mfma16(acc[mf][nf], ah[mf], bl[nf]);
        #pragma unroll
        for (int mf = 0; mf < 4; ++mf)
            #pragma unroll
            for (int nf = 0; nf < 4; ++nf)
                mfma16(acc[mf][nf], ah[mf], bh[nf]);

        // phase 3: land prefetched A into the other buffer (waits vmcnt here)
        if (t + 1 < NT) writeA(cur ^ 1, apf);

        __syncthreads();   // RAW for buf cur^1, WAR for buf cur — one barrier
    }

    asm volatile("s_nop 7\n\ts_nop 7" ::: );   // MFMA->VALU read hazard guard

    const int rb = row0 + wm * 64;
    const int cb = col0 + wn * 64;
    #pragma unroll
    for (int nf = 0; nf < 4; ++nf) {
        const int c = cb + nf * 16 + fr;                 // C/D: col = lane&15
        const float bv = bias[hop * OUT_DIM + c];
        #pragma unroll
        for (int mf = 0; mf < 4; ++mf) {
            #pragma unroll
            for (int j = 0; j < 4; ++j) {
                const int r = rb + mf * 16 + kg * 4 + j; // C/D: row = (lane>>4)*4+reg
                if (r < M) {
                    float v = acc[mf][nf][j] + bv;
                    out[(size_t)r * (3 * OUT_DIM) + hop * OUT_DIM + c] = v > 0.f ? v : 0.f;
                }
            }
        }
    }
}

// ---------------- launcher ----------------

extern "C" void kernel_launch(void* const* d_in, const int* in_sizes, int n_in,
                              void* d_out, int out_size, void* d_ws, size_t ws_size,
                              hipStream_t stream) {
    const float* features = (const float*)d_in[0];
    const float* D_norm   = (const float*)d_in[1];
    const float* edge_w   = (const float*)d_in[2];
    const float* W        = (const float*)d_in[3];
    const float* b        = (const float*)d_in[4];
    const int*   src      = (const int*)d_in[5];
    const int*   dst      = (const int*)d_in[6];
    const int N = in_sizes[1];   // D_norm is [N,1]
    const int E = in_sizes[2];
    float* out = (float*)d_out;

    char* w = (char*)d_ws;
    auto alloc = [&](size_t bytes) {
        void* p = (void*)w;
        w += (bytes + 255) & ~(size_t)255;
        return p;
    };
    int*            counts = (int*)alloc((size_t)N * 4);
    int*            offs   = (int*)alloc((size_t)(N + 1) * 4);
    int*            cursor = (int*)alloc((size_t)N * 4);
    int*            esrc   = (int*)alloc((size_t)E * 4);
    float*          eww    = (float*)alloc((size_t)E * 4);
    float*          h1     = (float*)alloc((size_t)N * IN_DIM * 4);
    float*          h2     = (float*)alloc((size_t)N * IN_DIM * 4);
    unsigned short* wthi   = (unsigned short*)alloc((size_t)3 * IN_DIM * OUT_DIM * 2);
    unsigned short* wtlo   = (unsigned short*)alloc((size_t)3 * IN_DIM * OUT_DIM * 2);

    hipMemsetAsync(counts, 0, (size_t)N * 4, stream);
    hist_kernel<<<(E + 255) / 256, 256, 0, stream>>>(dst, counts, E);
    scan_kernel<<<1, 1024, 0, stream>>>(counts, offs, cursor, N);
    scatter_kernel<<<(E + 255) / 256, 256, 0, stream>>>(src, dst, edge_w, cursor, esrc, eww, E);

    wsplit_kernel<<<(3 * IN_DIM * (OUT_DIM / 4)) / 256, 256, 0, stream>>>(W, wthi, wtlo);

    const int hop_blocks = ((N + 3) / 4) * 8;   // 4 nodes/block x 8 slices
    hop_slice_kernel<<<hop_blocks, 256, 0, stream>>>(features, D_norm, offs, esrc, eww, h1, N);
    hop_slice_kernel<<<hop_blocks, 256, 0, stream>>>(h1, D_norm, offs, esrc, eww, h2, N);

    dim3 grid((N + BM - 1) / BM, OUT_DIM / BN, 3);
    gemm_split_mfma<<<grid, 256, 0, stream>>>(features, h1, h2, wthi, wtlo, b, out, N);
}

// Round 13
// 286.007 us; speedup vs baseline: 1.0976x; 1.0976x over previous
//
#include <hip/hip_runtime.h>
#include <hip/hip_bf16.h>

// GCNLayer: CSR build + 2 SpMM hops (A/B: hop1 float4-unsliced vs hop2
// float2 4-slice XCD-affine) + 3 fused GEMMs via bf16 hi/lo split MFMA,
// double-buffered LDS 2-phase pipeline.
// out[r*1536 + hop*512 + c] = relu(h_hop @ W[hop] + b[hop])

#define IN_DIM 512
#define OUT_DIM 512

typedef float f32x4 __attribute__((ext_vector_type(4)));
typedef unsigned short u16x8 __attribute__((ext_vector_type(8)));

__device__ inline unsigned short f2bf(float x) {
    union { float f; unsigned u; } v; v.f = x;
    unsigned r = v.u + 0x7fff + ((v.u >> 16) & 1);   // round-to-nearest-even
    return (unsigned short)(r >> 16);
}
__device__ inline float bf2f(unsigned short h) {
    union { float f; unsigned u; } v; v.u = ((unsigned)h) << 16;
    return v.f;
}

__device__ inline void gld_lds16(const void* g, void* l) {
    __builtin_amdgcn_global_load_lds(
        (const __attribute__((address_space(1))) unsigned*)g,
        (__attribute__((address_space(3))) unsigned*)l, 16, 0, 0);
}

__device__ inline void mfma16(f32x4& d, u16x8 a, u16x8 b) {
    asm("v_mfma_f32_16x16x32_bf16 %0, %1, %2, %0" : "+v"(d) : "v"(a), "v"(b));
}

// ---------------- CSR build ----------------

__global__ __launch_bounds__(256) void hist_kernel(const int* __restrict__ dst,
                                                   int* __restrict__ counts, int E) {
    int e = blockIdx.x * blockDim.x + threadIdx.x;
    if (e < E) atomicAdd(&counts[dst[e]], 1);
}

__global__ __launch_bounds__(1024) void scan_kernel(const int* __restrict__ counts,
                                                    int* __restrict__ offs,
                                                    int* __restrict__ cursor, int n) {
    __shared__ int partials[16];
    const int tid = threadIdx.x;
    const int chunk = (n + 1023) / 1024;
    const int start = tid * chunk;
    const int end = min(start + chunk, n);

    int sum = 0;
    for (int i = start; i < end; ++i) sum += counts[i];

    const int lane = tid & 63;
    const int wave = tid >> 6;
    int v = sum;
    #pragma unroll
    for (int d = 1; d < 64; d <<= 1) {
        int up = __shfl_up(v, d, 64);
        if (lane >= d) v += up;
    }
    if (lane == 63) partials[wave] = v;
    __syncthreads();
    if (tid == 0) {
        int acc = 0;
        #pragma unroll
        for (int w = 0; w < 16; ++w) { int t = partials[w]; partials[w] = acc; acc += t; }
    }
    __syncthreads();

    int run = partials[wave] + (v - sum);
    for (int i = start; i < end; ++i) {
        offs[i] = run;
        cursor[i] = run;
        run += counts[i];
    }
    if (end == n) offs[n] = run;
}

__global__ __launch_bounds__(256) void scatter_kernel(const int* __restrict__ src,
                                                      const int* __restrict__ dst,
                                                      const float* __restrict__ edge_w,
                                                      int* __restrict__ cursor,
                                                      int* __restrict__ esrc,
                                                      float* __restrict__ eww, int E) {
    int e = blockIdx.x * blockDim.x + threadIdx.x;
    if (e < E) {
        int d = dst[e];
        int pos = atomicAdd(&cursor[d], 1);
        esrc[pos] = src[e];
        eww[pos] = edge_w[e];
    }
}

// ---------------- hop variant A: float4, unsliced (round-3 known-good) ----
// 1 node/block, 128 thr x float4 = 512 feats.

__global__ __launch_bounds__(128) void hop_f4_kernel(const float* __restrict__ hin,
                                                     const float* __restrict__ Dn,
                                                     const int* __restrict__ offs,
                                                     const int* __restrict__ esrc,
                                                     const float* __restrict__ eww,
                                                     float* __restrict__ hout) {
    const int v = blockIdx.x;
    const int t = threadIdx.x;
    const int beg = offs[v];
    const int end = offs[v + 1];
    float ax = 0.f, ay = 0.f, az = 0.f, aw = 0.f;
    int sN = 0; float wN = 0.f;
    if (beg < end) { sN = esrc[beg]; wN = eww[beg]; }
    for (int i = beg; i < end; ++i) {
        const int s = sN;
        const float w = wN;
        if (i + 1 < end) { sN = esrc[i + 1]; wN = eww[i + 1]; }  // uniform prefetch
        const float4 x = *(const float4*)&hin[(size_t)s * IN_DIM + t * 4];
        ax = fmaf(x.x, w, ax);
        ay = fmaf(x.y, w, ay);
        az = fmaf(x.z, w, az);
        aw = fmaf(x.w, w, aw);
    }
    const float d = Dn[v];
    float4 r = {ax * d, ay * d, az * d, aw * d};
    *(float4*)&hout[(size_t)v * IN_DIM + t * 4] = r;
}

// ---------------- hop variant B: float2, 4-slice XCD-affine -----------------
// slice = bid & 3 (128 cols, 5.12 MB): under bid%8->XCD round-robin, slice s
// lives on XCD pair {s, s+4} -> ~78% L2-resident gather. Wave = node (no
// divergence), 64 lanes x float2 = 128 cols. 4 nodes/block.

__global__ __launch_bounds__(256) void hop_s4_kernel(const float* __restrict__ hin,
                                                     const float* __restrict__ Dn,
                                                     const int* __restrict__ offs,
                                                     const int* __restrict__ esrc,
                                                     const float* __restrict__ eww,
                                                     float* __restrict__ hout, int N) {
    const int bid = blockIdx.x;
    const int slice = bid & 3;
    const int wv = threadIdx.x >> 6;
    const int v = (bid >> 2) * 4 + wv;
    if (v >= N) return;
    const int f = slice * 128 + (threadIdx.x & 63) * 2;

    const int beg = offs[v];
    const int end = offs[v + 1];
    float ax = 0.f, ay = 0.f;
    int sN = 0; float wN = 0.f;
    if (beg < end) { sN = esrc[beg]; wN = eww[beg]; }
    for (int i = beg; i < end; ++i) {
        const int s = sN;
        const float w = wN;
        if (i + 1 < end) { sN = esrc[i + 1]; wN = eww[i + 1]; }  // uniform prefetch
        const float2 x = *(const float2*)&hin[(size_t)s * IN_DIM + f];
        ax = fmaf(x.x, w, ax);
        ay = fmaf(x.y, w, ay);
    }
    const float d = Dn[v];
    float2 r = {ax * d, ay * d};
    *(float2*)&hout[(size_t)v * IN_DIM + f] = r;
}

// ---------------- W transpose + bf16 hi/lo split (once per launch) ----------
// W[hop][k][n] fp32 -> WtHi/WtLo[hop][n][k] bf16

__global__ __launch_bounds__(256) void wsplit_kernel(const float* __restrict__ W,
                                                     unsigned short* __restrict__ WtHi,
                                                     unsigned short* __restrict__ WtLo) {
    const int t = blockIdx.x * 256 + threadIdx.x;   // 3*512*128 total
    const int kq = t & 127;
    const int n = (t >> 7) & 511;
    const int h = t >> 16;
    const float* w = W + (size_t)h * IN_DIM * OUT_DIM;
    unsigned short hi[4], lo[4];
    #pragma unroll
    for (int j = 0; j < 4; ++j) {
        const float x = w[(size_t)(kq * 4 + j) * OUT_DIM + n];
        hi[j] = f2bf(x);
        lo[j] = f2bf(x - bf2f(hi[j]));
    }
    const size_t o = (size_t)h * IN_DIM * OUT_DIM + (size_t)n * IN_DIM + kq * 4;
    *(ushort4*)&WtHi[o] = *(const ushort4*)hi;
    *(ushort4*)&WtLo[o] = *(const ushort4*)lo;
}

// ---------------- split-bf16 MFMA GEMM + bias + relu (unchanged) -----------
// BM=BN=128, BK=32, 256 thr (4 waves, 2x2 of 64x64).
// Double-buffered LDS, 2-phase: issue stage(t+1) -> compute(t) -> write A(t+1)
// -> one barrier.

#define BM 128
#define BN 128
#define BK 32
#define NT (IN_DIM / BK)

__global__ __launch_bounds__(256) void gemm_split_mfma(
        const float* __restrict__ A0, const float* __restrict__ A1,
        const float* __restrict__ A2,
        const unsigned short* __restrict__ WtHi, const unsigned short* __restrict__ WtLo,
        const float* __restrict__ bias, float* __restrict__ out, int M) {

    // [buf][0=Ahi,1=Alo,2=Bhi,3=Blo][BM*BK] ushort: 2*4*8KB = 64 KB
    __shared__ unsigned short lds[2][4][BM * BK];

    const int tid = threadIdx.x;
    const int ln = tid & 63;
    const int wv = tid >> 6;
    const int hop = blockIdx.z;
    const float* __restrict__ A = hop == 0 ? A0 : hop == 1 ? A1 : A2;
    const unsigned short* __restrict__ BH = WtHi + (size_t)hop * IN_DIM * OUT_DIM;
    const unsigned short* __restrict__ BL = WtLo + (size_t)hop * IN_DIM * OUT_DIM;

    const int row0 = blockIdx.x * BM;
    const int col0 = blockIdx.y * BN;

    const int ar = tid >> 3;
    const int akq = tid & 7;
    const int bi = ln >> 2;
    const int bsl = ln & 3;

    const int wm = wv >> 1, wn = wv & 1;   // wave's 64x64 sub-tile
    const int fr = ln & 15, kg = ln >> 4;  // fragment row/col + k-group

    auto stageB = [&](int b, int k0) {
        #pragma unroll
        for (int q = 0; q < 2; ++q) {
            const int nrow = (wv * 2 + q) * 16 + bi;          // 0..127
            const int kp = bsl ^ ((nrow >> 1) & 3);           // swizzled 16B slot
            const size_t go = (size_t)(col0 + nrow) * IN_DIM + k0 + kp * 8;
            gld_lds16(BH + go, (char*)lds[b][2] + (wv * 2 + q) * 1024);
            gld_lds16(BL + go, (char*)lds[b][3] + (wv * 2 + q) * 1024);
        }
    };
    auto loadA = [&](float4* apf, int k0) {
        #pragma unroll
        for (int p = 0; p < 4; ++p) {
            int gr = row0 + ar + p * 32;
            gr = gr < M ? gr : M - 1;                         // clamp; never stored
            apf[p] = *(const float4*)&A[(size_t)gr * IN_DIM + k0 + akq * 4];
        }
    };
    auto writeA = [&](int b, const float4* apf) {
        #pragma unroll
        for (int p = 0; p < 4; ++p) {
            const int r = ar + p * 32;                        // 0..127
            const float4 av = apf[p];
            unsigned short h[4], l[4];
            h[0] = f2bf(av.x); l[0] = f2bf(av.x - bf2f(h[0]));
            h[1] = f2bf(av.y); l[1] = f2bf(av.y - bf2f(h[1]));
            h[2] = f2bf(av.z); l[2] = f2bf(av.z - bf2f(h[2]));
            h[3] = f2bf(av.w); l[3] = f2bf(av.w - bf2f(h[3]));
            const int boff = r * 64 + ((akq * 8) ^ ((((r >> 1) & 3)) << 4));
            *(ushort4*)((char*)lds[b][0] + boff) = *(const ushort4*)h;
            *(ushort4*)((char*)lds[b][1] + boff) = *(const ushort4*)l;
        }
    };

    f32x4 acc[4][4] = {};

    {
        stageB(0, 0);
        float4 apf[4];
        loadA(apf, 0);
        writeA(0, apf);
    }
    __syncthreads();

    #pragma unroll 1
    for (int t = 0; t < NT; ++t) {
        const int cur = t & 1;

        float4 apf[4];
        if (t + 1 < NT) {
            stageB(cur ^ 1, (t + 1) * BK);
            loadA(apf, (t + 1) * BK);
        }

        u16x8 ah[4], al[4], bh[4], bl[4];
        #pragma unroll
        for (int mf = 0; mf < 4; ++mf) {
            const int r = wm * 64 + mf * 16 + fr;
            const int off = r * 64 + ((kg * 16) ^ ((((r >> 1) & 3)) << 4));
            ah[mf] = *(const u16x8*)((const char*)lds[cur][0] + off);
            al[mf] = *(const u16x8*)((const char*)lds[cur][1] + off);
        }
        #pragma unroll
        for (int nf = 0; nf < 4; ++nf) {
            const int n = wn * 64 + nf * 16 + fr;
            const int off = n * 64 + ((kg * 16) ^ ((((n >> 1) & 3)) << 4));
            bh[nf] = *(const u16x8*)((const char*)lds[cur][2] + off);
            bl[nf] = *(const u16x8*)((const char*)lds[cur][3] + off);
        }

        #pragma unroll
        for (int mf = 0; mf < 4; ++mf)
            #pragma unroll
            for (int nf = 0; nf < 4; ++nf)
                mfma16(acc[mf][nf], al[mf], bh[nf]);
        #pragma unroll
        for (int mf = 0; mf < 4; ++mf)
            #pragma unroll
            for (int nf = 0; nf < 4; ++nf)
                mfma16(acc[mf][nf], ah[mf], bl[nf]);
        #pragma unroll
        for (int mf = 0; mf < 4; ++mf)
            #pragma unroll
            for (int nf = 0; nf < 4; ++nf)
                mfma16(acc[mf][nf], ah[mf], bh[nf]);

        if (t + 1 < NT) writeA(cur ^ 1, apf);

        __syncthreads();
    }

    asm volatile("s_nop 7\n\ts_nop 7" ::: );

    const int rb = row0 + wm * 64;
    const int cb = col0 + wn * 64;
    #pragma unroll
    for (int nf = 0; nf < 4; ++nf) {
        const int c = cb + nf * 16 + fr;                 // C/D: col = lane&15
        const float bv = bias[hop * OUT_DIM + c];
        #pragma unroll
        for (int mf = 0; mf < 4; ++mf) {
            #pragma unroll
            for (int j = 0; j < 4; ++j) {
                const int r = rb + mf * 16 + kg * 4 + j; // C/D: row = (lane>>4)*4+reg
                if (r < M) {
                    float v = acc[mf][nf][j] + bv;
                    out[(size_t)r * (3 * OUT_DIM) + hop * OUT_DIM + c] = v > 0.f ? v : 0.f;
                }
            }
        }
    }
}

// ---------------- launcher ----------------

extern "C" void kernel_launch(void* const* d_in, const int* in_sizes, int n_in,
                              void* d_out, int out_size, void* d_ws, size_t ws_size,
                              hipStream_t stream) {
    const float* features = (const float*)d_in[0];
    const float* D_norm   = (const float*)d_in[1];
    const float* edge_w   = (const float*)d_in[2];
    const float* W        = (const float*)d_in[3];
    const float* b        = (const float*)d_in[4];
    const int*   src      = (const int*)d_in[5];
    const int*   dst      = (const int*)d_in[6];
    const int N = in_sizes[1];   // D_norm is [N,1]
    const int E = in_sizes[2];
    float* out = (float*)d_out;

    char* w = (char*)d_ws;
    auto alloc = [&](size_t bytes) {
        void* p = (void*)w;
        w += (bytes + 255) & ~(size_t)255;
        return p;
    };
    int*            counts = (int*)alloc((size_t)N * 4);
    int*            offs   = (int*)alloc((size_t)(N + 1) * 4);
    int*            cursor = (int*)alloc((size_t)N * 4);
    int*            esrc   = (int*)alloc((size_t)E * 4);
    float*          eww    = (float*)alloc((size_t)E * 4);
    float*          h1     = (float*)alloc((size_t)N * IN_DIM * 4);
    float*          h2     = (float*)alloc((size_t)N * IN_DIM * 4);
    unsigned short* wthi   = (unsigned short*)alloc((size_t)3 * IN_DIM * OUT_DIM * 2);
    unsigned short* wtlo   = (unsigned short*)alloc((size_t)3 * IN_DIM * OUT_DIM * 2);

    hipMemsetAsync(counts, 0, (size_t)N * 4, stream);
    hist_kernel<<<(E + 255) / 256, 256, 0, stream>>>(dst, counts, E);
    scan_kernel<<<1, 1024, 0, stream>>>(counts, offs, cursor, N);
    scatter_kernel<<<(E + 255) / 256, 256, 0, stream>>>(src, dst, edge_w, cursor, esrc, eww, E);

    wsplit_kernel<<<(3 * IN_DIM * (OUT_DIM / 4)) / 256, 256, 0, stream>>>(W, wthi, wtlo);

    // A/B: hop1 = float4 unsliced (known-good), hop2 = float2 4-slice affine
    hop_f4_kernel<<<N, 128, 0, stream>>>(features, D_norm, offs, esrc, eww, h1);
    const int s4_blocks = ((N + 3) / 4) * 4;
    hop_s4_kernel<<<s4_blocks, 256, 0, stream>>>(h1, D_norm, offs, esrc, eww, h2, N);

    dim3 grid((N + BM - 1) / BM, OUT_DIM / BN, 3);
    gemm_split_mfma<<<grid, 256, 0, stream>>>(features, h1, h2, wthi, wtlo, b, out, N);
}